// Round 3
// baseline (206.387 us; speedup 1.0000x reference)
//
#include <hip/hip_runtime.h>
#include <hip/hip_bf16.h>

#define BB 8
#define CC 128
#define NN 4096
#define LOG2E 1.44269504088896340736f

typedef __attribute__((ext_vector_type(4))) float f32x4;
typedef __attribute__((ext_vector_type(4))) short s16x4;
typedef __attribute__((ext_vector_type(8))) short s16x8;

__device__ inline short f2bf(float f){
  unsigned u = __float_as_uint(f);
  u += 0x7FFFu + ((u >> 16) & 1u);
  return (short)(u >> 16);
}
__device__ inline float bf2f(short s){
  return __uint_as_float(((unsigned)(unsigned short)s) << 16);
}
// pack hi16(e0) | hi16(e1)<<16 (truncation) in one v_perm_b32
__device__ inline unsigned pack2(float e0, float e1){
  return __builtin_amdgcn_perm(__float_as_uint(e1), __float_as_uint(e0), 0x07060302u);
}
// within-64 column permutation for hP: n-slot -> physical slot
__device__ inline int permn(int t){
  return (t & 32) | (((t >> 2) & 3) << 3) | (((t >> 4) & 1) << 2) | (t & 3);
}

// ---------------- K1: projections. f scaled by log2e; h written permuted ----------------
__global__ __launch_bounds__(256) void k_proj(
    const float* __restrict__ x,  const float* __restrict__ Wf, const float* __restrict__ bf,
    const float* __restrict__ Wg, const float* __restrict__ bg,
    const float* __restrict__ Wh, const float* __restrict__ bh,
    short* __restrict__ fT, short* __restrict__ gT, short* __restrict__ hP)
{
  __shared__ float xt[128][64];
  const int blk   = blockIdx.x;
  const int b     = blk & 7;
  const int ntile = (blk >> 3) & 63;
  const int cog   = blk >> 9;
  const int n0    = ntile * 64;
  const int tid   = threadIdx.x;

  for (int idx = tid; idx < 128*64; idx += 256){
    int c = idx >> 6, j = idx & 63;
    xt[c][j] = x[((size_t)(b*128 + c))*NN + n0 + j];
  }
  __syncthreads();

  const int nl  = tid & 63;
  const int sub = __builtin_amdgcn_readfirstlane(tid >> 6);
  const int cobase = cog*40 + sub*10;

  const float* wr[10]; float bias[10];
  #pragma unroll
  for (int i=0;i<10;++i){
    int co = cobase + i;
    if (co < 16)      { wr[i] = Wf + co*128;      bias[i] = bf[co];    }
    else if (co < 32) { wr[i] = Wg + (co-16)*128; bias[i] = bg[co-16]; }
    else              { wr[i] = Wh + (co-32)*128; bias[i] = bh[co-32]; }
  }

  float acc[10];
  #pragma unroll
  for (int i=0;i<10;++i) acc[i] = 0.f;

  for (int c=0;c<128;++c){
    float xv = xt[c][nl];
    #pragma unroll
    for (int i=0;i<10;++i) acc[i] += wr[i][c]*xv;
  }

  const int n  = n0 + nl;
  const int pn = n0 + permn(nl);
  #pragma unroll
  for (int i=0;i<10;++i){
    int co = cobase + i;
    float v = acc[i] + bias[i];
    if (co < 16)      fT[((size_t)b*NN + n)*16 + co]        = f2bf(v * LOG2E);
    else if (co < 32) gT[((size_t)b*NN + n)*16 + (co-16)]   = f2bf(v);
    else              hP[((size_t)(b*CC + (co-32)))*NN + pn] = f2bf(v);
  }
}

// ---------------- K2: rs[n] = sum_m exp2(S'), then hP[c][n] *= gamma/rs[n] ----------------
__global__ __launch_bounds__(256,4) void k_stats(
    const short* __restrict__ fT, const short* __restrict__ gT,
    const float* __restrict__ gamma, short* __restrict__ hP)
{
  __shared__ float sscale[64];
  const int blk = blockIdx.x;
  const int b = blk & 7, ntile = blk >> 3;
  const int n0 = ntile * 64;
  const int tid = threadIdx.x;
  const int w = tid >> 6, l = tid & 63;
  const int g = l >> 4, lm = l & 15;
  const f32x4 zero4 = {0.f,0.f,0.f,0.f};

  s16x4 f4 = *(const s16x4*)(fT + ((size_t)b*NN + n0 + w*16 + lm)*16 + 4*g);
  s16x8 fa = {f4[0],f4[1],f4[2],f4[3],0,0,0,0};

  const short* gb_base = gT + ((size_t)b*NN + lm)*16 + 4*g;

  f32x4 rs = {0.f,0.f,0.f,0.f};
  s16x4 gc[4], gn[4];
  #pragma unroll
  for (int j=0;j<4;++j) gc[j] = *(const s16x4*)(gb_base + j*256);

  #pragma unroll 1
  for (int m0 = 0; m0 < NN; m0 += 64){
    if (m0 < NN-64){
      #pragma unroll
      for (int j=0;j<4;++j) gn[j] = *(const s16x4*)(gb_base + (m0+64)*16 + j*256);
    }
    #pragma unroll
    for (int j=0;j<4;++j){
      s16x8 gb = {gc[j][0],gc[j][1],gc[j][2],gc[j][3],0,0,0,0};
      f32x4 d = __builtin_amdgcn_mfma_f32_16x16x32_bf16(fa, gb, zero4, 0,0,0);
      #pragma unroll
      for (int i=0;i<4;++i) rs[i] += __builtin_amdgcn_exp2f(d[i]);
    }
    #pragma unroll
    for (int j=0;j<4;++j) gc[j] = gn[j];
  }

  #pragma unroll
  for (int i=0;i<4;++i){
    #pragma unroll
    for (int mask=1; mask<16; mask<<=1) rs[i] += __shfl_xor(rs[i], mask);
  }
  if (lm == 0){
    const float gm = gamma[0];
    #pragma unroll
    for (int i=0;i<4;++i) sscale[w*16 + 4*g + i] = gm / rs[i];
  }
  __syncthreads();

  // scale hP columns [n0, n0+64) in place (physical-permuted layout)
  #pragma unroll
  for (int jj=0; jj<4; ++jj){
    const int id = jj*256 + tid;
    const int q  = tid & 7;
    const int c  = id >> 3;
    short* p = hP + ((size_t)(b*CC + c))*NN + n0 + q*8;
    s16x8 v = *(const s16x8*)p;
    const int t0 = ((q>>2)<<5) | ((q&3)<<2);
    f32x4 slo = *(const f32x4*)&sscale[t0];
    f32x4 shi = *(const f32x4*)&sscale[t0+16];
    s16x8 o;
    #pragma unroll
    for (int e=0;e<4;++e){
      o[e]   = f2bf(bf2f(v[e])   * slo[e]);
      o[4+e] = f2bf(bf2f(v[4+e]) * shi[e]);
    }
    *(s16x8*)p = o;
  }
}

// ---------------- K3: out = x + sum_n hP[c][n] * exp2(S'[n][m]) ----------------
// block 256 = 4 waves = 2 m-waves(32 m) x 2 n-halves. LDS dbuf 64KB, 1 barrier/iter.
__global__ __launch_bounds__(256,2) void k_attend(
    const float* __restrict__ x, const short* __restrict__ fT, const short* __restrict__ gT,
    const short* __restrict__ hP, float* __restrict__ out)
{
  __shared__ __align__(16) char hlds[65536];

  const int blk = blockIdx.x;
  const int b = blk & 7, mtile = blk >> 3;
  const int tid = threadIdx.x;
  const int w = tid >> 6, l = tid & 63;
  const int g = l >> 4, lm = l & 15;
  const int mw = w & 1, nh = w >> 1;
  const int m0w = mtile*64 + mw*32;
  const int nbase = nh*2048;
  const f32x4 zero4 = {0.f,0.f,0.f,0.f};

  // staging addressing: chunk id = j*128 + tid2 ; q = id&7 (const), c = j*16 + (tid2>>3)
  const int tid2 = mw*64 + l;
  const int sq = tid2 & 7;
  const int sr = tid2 >> 3;
  const char* hPb = (const char*)(hP + (size_t)b*CC*NN);
  const int goff0 = sr*8192 + sq*16 + nbase*2;
  char* ldsw0 = hlds + nh*32768 + (sq*128 + sr)*16;         // + buf*16384 + j*256
  const char* ldsr0 = hlds + nh*32768 + (g*128 + lm)*16;    // + buf*16384 + H*8192 + cs*256

  s16x4 g40 = *(const s16x4*)(gT + ((size_t)b*NN + m0w      + lm)*16 + 4*g);
  s16x4 g41 = *(const s16x4*)(gT + ((size_t)b*NN + m0w + 16 + lm)*16 + 4*g);
  s16x8 gb0 = {g40[0],g40[1],g40[2],g40[3],0,0,0,0};
  s16x8 gb1 = {g41[0],g41[1],g41[2],g41[3],0,0,0,0};

  const short* fTb = fT + ((size_t)b*NN + nbase + lm)*16 + 4*g;

  f32x4 acc[2][8];
  #pragma unroll
  for (int h=0;h<2;++h)
    #pragma unroll
    for (int cs=0;cs<8;++cs) acc[h][cs] = zero4;

  s16x8 sreg[8];
  s16x4 fa_c[4], fa_n[4];

  // prologue: stage it=0 into buf0; fa(0); issue loads for it=1
  #pragma unroll
  for (int j=0;j<8;++j) sreg[j] = *(const s16x8*)(hPb + goff0 + j*131072);
  #pragma unroll
  for (int j=0;j<8;++j) *(s16x8*)(ldsw0 + j*256) = sreg[j];
  #pragma unroll
  for (int j=0;j<4;++j) fa_c[j] = *(const s16x4*)(fTb + j*256);
  #pragma unroll
  for (int j=0;j<8;++j) sreg[j] = *(const s16x8*)(hPb + goff0 + j*131072 + 128);
  __syncthreads();

  #pragma unroll 1
  for (int it=0; it<32; ++it){
    const int buf = it & 1;
    // write data(it+1) into buf^1 (safe: buf^1 last read at it-1)
    if (it < 31){
      char* wb = ldsw0 + (buf^1)*16384;
      #pragma unroll
      for (int j=0;j<8;++j) *(s16x8*)(wb + j*256) = sreg[j];
    }
    // issue loads for it+2
    if (it < 30){
      #pragma unroll
      for (int j=0;j<8;++j) sreg[j] = *(const s16x8*)(hPb + goff0 + j*131072 + (it+2)*128);
    }
    // fa for it+1
    if (it < 31){
      #pragma unroll
      for (int j=0;j<4;++j) fa_n[j] = *(const s16x4*)(fTb + (it+1)*1024 + j*256);
    }

    const char* rb = ldsr0 + buf*16384;
    #pragma unroll
    for (int H=0; H<2; ++H){
      s16x8 fa0 = {fa_c[2*H][0],  fa_c[2*H][1],  fa_c[2*H][2],  fa_c[2*H][3],  0,0,0,0};
      s16x8 fa1 = {fa_c[2*H+1][0],fa_c[2*H+1][1],fa_c[2*H+1][2],fa_c[2*H+1][3],0,0,0,0};
      f32x4 dA0 = __builtin_amdgcn_mfma_f32_16x16x32_bf16(fa0, gb0, zero4, 0,0,0);
      f32x4 dB0 = __builtin_amdgcn_mfma_f32_16x16x32_bf16(fa1, gb0, zero4, 0,0,0);
      f32x4 dA1 = __builtin_amdgcn_mfma_f32_16x16x32_bf16(fa0, gb1, zero4, 0,0,0);
      f32x4 dB1 = __builtin_amdgcn_mfma_f32_16x16x32_bf16(fa1, gb1, zero4, 0,0,0);

      union { unsigned u[4]; s16x8 v; } A0, A1;
      A0.u[0] = pack2(__builtin_amdgcn_exp2f(dA0[0]), __builtin_amdgcn_exp2f(dA0[1]));
      A0.u[1] = pack2(__builtin_amdgcn_exp2f(dA0[2]), __builtin_amdgcn_exp2f(dA0[3]));
      A0.u[2] = pack2(__builtin_amdgcn_exp2f(dB0[0]), __builtin_amdgcn_exp2f(dB0[1]));
      A0.u[3] = pack2(__builtin_amdgcn_exp2f(dB0[2]), __builtin_amdgcn_exp2f(dB0[3]));
      A1.u[0] = pack2(__builtin_amdgcn_exp2f(dA1[0]), __builtin_amdgcn_exp2f(dA1[1]));
      A1.u[1] = pack2(__builtin_amdgcn_exp2f(dA1[2]), __builtin_amdgcn_exp2f(dA1[3]));
      A1.u[2] = pack2(__builtin_amdgcn_exp2f(dB1[0]), __builtin_amdgcn_exp2f(dB1[1]));
      A1.u[3] = pack2(__builtin_amdgcn_exp2f(dB1[2]), __builtin_amdgcn_exp2f(dB1[3]));

      #pragma unroll
      for (int cs=0; cs<8; ++cs){
        s16x8 hb = *(const s16x8*)(rb + H*8192 + cs*256);
        acc[0][cs] = __builtin_amdgcn_mfma_f32_16x16x32_bf16(A0.v, hb, acc[0][cs], 0,0,0);
        acc[1][cs] = __builtin_amdgcn_mfma_f32_16x16x32_bf16(A1.v, hb, acc[1][cs], 0,0,0);
      }
    }
    #pragma unroll
    for (int j=0;j<4;++j) fa_c[j] = fa_n[j];
    __syncthreads();
  }

  // cross-half reduction + epilogue (gamma pre-folded into hP)
  float* red = (float*)hlds;   // red[c][68]
  if (nh == 1){
    #pragma unroll
    for (int h=0;h<2;++h)
      #pragma unroll
      for (int cs=0;cs<8;++cs)
        *(f32x4*)&red[(cs*16+lm)*68 + mw*32 + h*16 + 4*g] = acc[h][cs];
  }
  __syncthreads();
  if (nh == 0){
    #pragma unroll
    for (int h=0;h<2;++h)
      #pragma unroll
      for (int cs=0;cs<8;++cs){
        const int c = cs*16 + lm;
        f32x4 r = *(const f32x4*)&red[c*68 + mw*32 + h*16 + 4*g];
        f32x4 a = acc[h][cs] + r;
        const size_t base = ((size_t)(b*CC + c))*NN + m0w + h*16 + 4*g;
        f32x4 xv = *(const f32x4*)(x + base);
        f32x4 ov;
        #pragma unroll
        for (int i=0;i<4;++i) ov[i] = xv[i] + a[i];
        *(f32x4*)(out + base) = ov;
      }
  }
}

extern "C" void kernel_launch(void* const* d_in, const int* in_sizes, int n_in,
                              void* d_out, int out_size, void* d_ws, size_t ws_size,
                              hipStream_t stream)
{
  const float* x     = (const float*)d_in[0];
  const float* Wf    = (const float*)d_in[1];
  const float* bf    = (const float*)d_in[2];
  const float* Wg    = (const float*)d_in[3];
  const float* bg    = (const float*)d_in[4];
  const float* Wh    = (const float*)d_in[5];
  const float* bh    = (const float*)d_in[6];
  const float* gamma = (const float*)d_in[7];
  float* out = (float*)d_out;

  short* fT = (short*)d_ws;                 // [B][N][16] bf16, *log2e
  short* gT = fT + (size_t)BB*NN*16;        // [B][N][16] bf16
  short* hP = gT + (size_t)BB*NN*16;        // [B][C][N]  bf16, permuted cols, later *gamma/rs

  k_proj  <<<BB*64*4, 256, 0, stream>>>(x, Wf, bf, Wg, bg, Wh, bh, fT, gT, hP);
  k_stats <<<BB*64,   256, 0, stream>>>(fT, gT, gamma, hP);
  k_attend<<<BB*64,   256, 0, stream>>>(x, fT, gT, hP, out);
}

// Round 4
// 173.323 us; speedup vs baseline: 1.1908x; 1.1908x over previous
//
#include <hip/hip_runtime.h>
#include <hip/hip_bf16.h>

#define BB 8
#define CC 128
#define NN 4096
#define LOG2E 1.44269504088896340736f

typedef __attribute__((ext_vector_type(4))) float f32x4;
typedef __attribute__((ext_vector_type(4))) short s16x4;
typedef __attribute__((ext_vector_type(8))) short s16x8;

__device__ inline short f2bf(float f){
  unsigned u = __float_as_uint(f);
  u += 0x7FFFu + ((u >> 16) & 1u);
  return (short)(u >> 16);
}
// low16 = bf16(e0), high16 = bf16(e1), truncation
__device__ inline unsigned pack2(float e0, float e1){
  return __builtin_amdgcn_perm(__float_as_uint(e1), __float_as_uint(e0), 0x07060302u);
}

// ---------------- K1: projections. fT *= log2e; hP written in MFMA-fragment layout ----------------
// hP[b][nc][row][e], row = (c>>4)*64 + g*16 + (c&15); n = nc*32 + {4g+e | e<4 ; 16+4g+(e-4)}
__global__ __launch_bounds__(512) void k_proj(
    const float* __restrict__ x,  const float* __restrict__ Wf, const float* __restrict__ bf,
    const float* __restrict__ Wg, const float* __restrict__ bg,
    const float* __restrict__ Wh, const float* __restrict__ bh,
    short* __restrict__ fT, short* __restrict__ gT, short* __restrict__ hP)
{
  __shared__ float xt[128][64];
  const int blk = blockIdx.x;
  const int b = blk & 7;
  const int ntile = blk >> 3;
  const int n0 = ntile * 64;
  const int tid = threadIdx.x;

  for (int idx = tid; idx < 128*64; idx += 512){
    int c = idx >> 6, j = idx & 63;
    xt[c][j] = x[((size_t)(b*128 + c))*NN + n0 + j];
  }
  __syncthreads();

  const int l = tid & 63;
  const int w = __builtin_amdgcn_readfirstlane(tid >> 6);
  const int cobase = w * 20;

  const float* wr[20]; float bias[20];
  #pragma unroll
  for (int i=0;i<20;++i){
    int co = cobase + i;
    if (co < 16)      { wr[i] = Wf + co*128;      bias[i] = bf[co];    }
    else if (co < 32) { wr[i] = Wg + (co-16)*128; bias[i] = bg[co-16]; }
    else              { wr[i] = Wh + (co-32)*128; bias[i] = bh[co-32]; }
  }

  float acc[20];
  #pragma unroll
  for (int i=0;i<20;++i) acc[i] = 0.f;

  for (int c=0;c<128;++c){
    float xv = xt[c][l];
    #pragma unroll
    for (int i=0;i<20;++i) acc[i] += wr[i][c]*xv;
  }

  const int n  = n0 + l;
  const int nc = n >> 5, ns = n & 31;
  const int sg = (ns >> 2) & 3;
  const int se = (ns & 3) + ((ns >> 4) << 2);
  #pragma unroll
  for (int i=0;i<20;++i){
    int co = cobase + i;
    float v = acc[i] + bias[i];
    if (co < 16)      fT[((size_t)b*NN + n)*16 + co]      = f2bf(v * LOG2E);
    else if (co < 32) gT[((size_t)b*NN + n)*16 + (co-16)] = f2bf(v);
    else {
      int c = co - 32;
      int row = ((c >> 4) << 6) + (sg << 4) + (c & 15);
      hP[(((size_t)(b*128 + nc))*512 + row)*8 + se] = f2bf(v);
    }
  }
}

// ---------------- K2: L[n] = -log2( sum_m exp2(S'[n][m]) ) ----------------
// 512 th = 4 n-slices(16n) x 2 m-halves(2048m); LDS merge.
__global__ __launch_bounds__(512,4) void k_stats(
    const short* __restrict__ fT, const short* __restrict__ gT, float* __restrict__ Lrow)
{
  __shared__ float sm[2][4][16];
  const int blk = blockIdx.x;
  const int b = blk & 7, ntile = blk >> 3;
  const int tid = threadIdx.x;
  const int w = tid >> 6, l = tid & 63;
  const int g = l >> 4, lm = l & 15;
  const int ns = w & 3, mh = w >> 2;
  const int n0 = ntile*64 + ns*16;
  const f32x4 zero4 = {0.f,0.f,0.f,0.f};

  s16x4 f4 = *(const s16x4*)(fT + ((size_t)b*NN + n0 + lm)*16 + 4*g);
  s16x8 fa = {f4[0],f4[1],f4[2],f4[3],0,0,0,0};

  const short* gTb = gT + ((size_t)b*NN + mh*2048 + lm)*16 + 4*g;

  f32x4 rs = {0.f,0.f,0.f,0.f};
  #pragma unroll 1
  for (int it=0; it<32; ++it){
    #pragma unroll
    for (int j=0;j<4;++j){
      s16x4 g4 = *(const s16x4*)(gTb + it*1024 + j*256);
      s16x8 gb = {g4[0],g4[1],g4[2],g4[3],0,0,0,0};
      f32x4 d = __builtin_amdgcn_mfma_f32_16x16x32_bf16(fa, gb, zero4, 0,0,0);
      #pragma unroll
      for (int i=0;i<4;++i) rs[i] += __builtin_amdgcn_exp2f(d[i]);
    }
  }
  #pragma unroll
  for (int i=0;i<4;++i){
    #pragma unroll
    for (int mask=1; mask<16; mask<<=1) rs[i] += __shfl_xor(rs[i], mask);
  }
  if (lm == 0){
    #pragma unroll
    for (int i=0;i<4;++i) sm[mh][ns][4*g+i] = rs[i];
  }
  __syncthreads();
  if (mh == 0 && lm == 0){
    #pragma unroll
    for (int i=0;i<4;++i){
      float z = rs[i] + sm[1][ns][4*g+i];
      Lrow[(size_t)b*NN + n0 + 4*g + i] = -__log2f(z);
    }
  }
}

// ---------------- K3: out = x + gamma * sum_n h[c][n] * exp2(S'[n][m] + L[n]) ----------------
// 512 th = 2 m-waves(32m) x 4 n-quarters(1024n). mtile 64, grid 512.
// LDS: 4 streams x ring2 x 8KB = 64KB. All LDS ops are 64-consecutive-16B-row patterns.
__global__ __launch_bounds__(512,4) void k_attend(
    const float* __restrict__ x, const short* __restrict__ fT, const short* __restrict__ gT,
    const short* __restrict__ hP, const float* __restrict__ Lrow,
    const float* __restrict__ gamma, float* __restrict__ out)
{
  __shared__ __align__(16) char lds[65536];

  const int blk = blockIdx.x;
  const int b = blk & 7, mtile = blk >> 3;
  const int tid = threadIdx.x;
  const int w = tid >> 6, l = tid & 63;
  const int g = l >> 4, lm = l & 15;
  const int mw = w & 1, nq = w >> 1;
  const int m0w = mtile*64 + mw*32;
  const int nbase = nq*1024;
  const f32x4 zero4 = {0.f,0.f,0.f,0.f};

  char* ring = lds + nq*16384;                       // 2 x 8KB bufs for this n-stream

  const short* hPs = hP + ((size_t)b*128 + nq*32)*4096;   // chunk = 4096 shorts
  const short* fTb = fT + ((size_t)b*NN + nbase + lm)*16 + 4*g;
  const float* Lb  = Lrow + (size_t)b*NN + nbase + 4*g;

  s16x4 g40 = *(const s16x4*)(gT + ((size_t)b*NN + m0w      + lm)*16 + 4*g);
  s16x4 g41 = *(const s16x4*)(gT + ((size_t)b*NN + m0w + 16 + lm)*16 + 4*g);
  s16x8 gb0 = {g40[0],g40[1],g40[2],g40[3],0,0,0,0};
  s16x8 gb1 = {g41[0],g41[1],g41[2],g41[3],0,0,0,0};

  f32x4 acc0[8], acc1[8];
  #pragma unroll
  for (int cs=0;cs<8;++cs){ acc0[cs] = zero4; acc1[cs] = zero4; }

  s16x8 sreg[4];
  // prologue: stage chunk 0
  {
    const short* src = hPs + mw*2048 + l*8;
    #pragma unroll
    for (int j=0;j<4;++j) sreg[j] = *(const s16x8*)(src + j*512);
    char* wb = ring + (mw*256 + l)*16;
    #pragma unroll
    for (int j=0;j<4;++j) *(s16x8*)(wb + j*1024) = sreg[j];
  }
  __syncthreads();

  #pragma unroll 1
  for (int it=0; it<32; ++it){
    const int buf = it & 1;
    if (it < 31){                                 // T14: issue next chunk's loads early
      const short* src = hPs + (it+1)*4096 + mw*2048 + l*8;
      #pragma unroll
      for (int j=0;j<4;++j) sreg[j] = *(const s16x8*)(src + j*512);
    }

    s16x4 fa4a = *(const s16x4*)(fTb + it*512);
    s16x4 fa4b = *(const s16x4*)(fTb + it*512 + 256);
    f32x4 C0 = *(const f32x4*)(Lb + it*32);
    f32x4 C1 = *(const f32x4*)(Lb + it*32 + 16);
    s16x8 fa0 = {fa4a[0],fa4a[1],fa4a[2],fa4a[3],0,0,0,0};
    s16x8 fa1 = {fa4b[0],fa4b[1],fa4b[2],fa4b[3],0,0,0,0};

    f32x4 d00 = __builtin_amdgcn_mfma_f32_16x16x32_bf16(fa0, gb0, C0, 0,0,0);
    f32x4 d10 = __builtin_amdgcn_mfma_f32_16x16x32_bf16(fa1, gb0, C1, 0,0,0);
    f32x4 d01 = __builtin_amdgcn_mfma_f32_16x16x32_bf16(fa0, gb1, C0, 0,0,0);
    f32x4 d11 = __builtin_amdgcn_mfma_f32_16x16x32_bf16(fa1, gb1, C1, 0,0,0);

    union { unsigned u[4]; s16x8 v; } A0, A1;
    A0.u[0] = pack2(__builtin_amdgcn_exp2f(d00[0]), __builtin_amdgcn_exp2f(d00[1]));
    A0.u[1] = pack2(__builtin_amdgcn_exp2f(d00[2]), __builtin_amdgcn_exp2f(d00[3]));
    A0.u[2] = pack2(__builtin_amdgcn_exp2f(d10[0]), __builtin_amdgcn_exp2f(d10[1]));
    A0.u[3] = pack2(__builtin_amdgcn_exp2f(d10[2]), __builtin_amdgcn_exp2f(d10[3]));
    A1.u[0] = pack2(__builtin_amdgcn_exp2f(d01[0]), __builtin_amdgcn_exp2f(d01[1]));
    A1.u[1] = pack2(__builtin_amdgcn_exp2f(d01[2]), __builtin_amdgcn_exp2f(d01[3]));
    A1.u[2] = pack2(__builtin_amdgcn_exp2f(d11[0]), __builtin_amdgcn_exp2f(d11[1]));
    A1.u[3] = pack2(__builtin_amdgcn_exp2f(d11[2]), __builtin_amdgcn_exp2f(d11[3]));

    const char* rb = ring + buf*8192 + l*16;
    #pragma unroll
    for (int cs=0; cs<8; ++cs){
      s16x8 hb = *(const s16x8*)(rb + cs*1024);
      acc0[cs] = __builtin_amdgcn_mfma_f32_16x16x32_bf16(A0.v, hb, acc0[cs], 0,0,0);
      acc1[cs] = __builtin_amdgcn_mfma_f32_16x16x32_bf16(A1.v, hb, acc1[cs], 0,0,0);
    }
    __syncthreads();                              // all reads of buf done
    if (it < 31){
      char* wb = ring + (buf^1)*8192 + (mw*256 + l)*16;
      #pragma unroll
      for (int j=0;j<4;++j) *(s16x8*)(wb + j*1024) = sreg[j];
    }
    __syncthreads();                              // staging visible
  }

  // 4-way n-quarter reduction: nq1->redA, nq3->redB; nq0+=redA, nq2+=redB; nq2->redA; nq0+=redA
  float* redA = (float*)lds;
  float* redB = (float*)(lds + 32768);
  if (nq == 1 || nq == 3){
    float* rp = (nq==1)? redA : redB;
    #pragma unroll
    for (int h=0; h<2; ++h)
      #pragma unroll
      for (int cs=0; cs<8; ++cs)
        *(f32x4*)(rp + (((h*8+cs)*2 + mw)*64 + l)*4) = h ? acc1[cs] : acc0[cs];
  }
  __syncthreads();
  if (nq == 0 || nq == 2){
    const float* rp = (nq==0)? redA : redB;
    #pragma unroll
    for (int h=0; h<2; ++h)
      #pragma unroll
      for (int cs=0; cs<8; ++cs){
        f32x4 r = *(const f32x4*)(rp + (((h*8+cs)*2 + mw)*64 + l)*4);
        if (h) acc1[cs] += r; else acc0[cs] += r;
      }
  }
  __syncthreads();
  if (nq == 2){
    #pragma unroll
    for (int h=0; h<2; ++h)
      #pragma unroll
      for (int cs=0; cs<8; ++cs)
        *(f32x4*)(redA + (((h*8+cs)*2 + mw)*64 + l)*4) = h ? acc1[cs] : acc0[cs];
  }
  __syncthreads();
  if (nq == 0){
    const float gm = gamma[0];
    #pragma unroll
    for (int h=0; h<2; ++h)
      #pragma unroll
      for (int cs=0; cs<8; ++cs){
        f32x4 r = *(const f32x4*)(redA + (((h*8+cs)*2 + mw)*64 + l)*4);
        f32x4 a = (h ? acc1[cs] : acc0[cs]) + r;
        const int c = cs*16 + lm;
        const size_t base = ((size_t)(b*128 + c))*NN + m0w + h*16 + 4*g;
        f32x4 xv = *(const f32x4*)(x + base);
        f32x4 ov;
        #pragma unroll
        for (int i=0;i<4;++i) ov[i] = xv[i] + gm*a[i];
        *(f32x4*)(out + base) = ov;
      }
  }
}

extern "C" void kernel_launch(void* const* d_in, const int* in_sizes, int n_in,
                              void* d_out, int out_size, void* d_ws, size_t ws_size,
                              hipStream_t stream)
{
  const float* x     = (const float*)d_in[0];
  const float* Wf    = (const float*)d_in[1];
  const float* bf    = (const float*)d_in[2];
  const float* Wg    = (const float*)d_in[3];
  const float* bg    = (const float*)d_in[4];
  const float* Wh    = (const float*)d_in[5];
  const float* bh    = (const float*)d_in[6];
  const float* gamma = (const float*)d_in[7];
  float* out = (float*)d_out;

  short* fT   = (short*)d_ws;                    // [B][N][16] bf16 (*log2e)
  short* gT   = fT + (size_t)BB*NN*16;           // [B][N][16] bf16
  short* hP   = gT + (size_t)BB*NN*16;           // [B][128nc][512row][8e] bf16 fragment layout
  float* Lrow = (float*)(hP + (size_t)BB*CC*NN); // [B][N]

  k_proj  <<<BB*64, 512, 0, stream>>>(x, Wf, bf, Wg, bg, Wh, bh, fT, gT, hP);
  k_stats <<<BB*64, 512, 0, stream>>>(fT, gT, Lrow);
  k_attend<<<BB*64, 512, 0, stream>>>(x, fT, gT, hP, Lrow, gamma, out);
}

// Round 5
// 99.197 us; speedup vs baseline: 2.0806x; 1.7473x over previous
//
#include <hip/hip_runtime.h>
#include <hip/hip_bf16.h>

#define BB 8
#define CC 128
#define NN 4096
#define LOG2E 1.44269504088896340736f

typedef __attribute__((ext_vector_type(4))) float f32x4;
typedef __attribute__((ext_vector_type(4))) short s16x4;
typedef __attribute__((ext_vector_type(8))) short s16x8;

__device__ inline short f2bf(float f){
  unsigned u = __float_as_uint(f);
  u += 0x7FFFu + ((u >> 16) & 1u);
  return (short)(u >> 16);
}
// low16 = bf16(e0), high16 = bf16(e1), truncation
__device__ inline unsigned pack2(float e0, float e1){
  return __builtin_amdgcn_perm(__float_as_uint(e1), __float_as_uint(e0), 0x07060302u);
}

// read one MFMA operand fragment from a swizzled LDS tile:
// element (row, c) lives at byte row*256 + ((c>>2)^(row&31))*8 + (c&3)*2
__device__ inline s16x8 frag_read(const char* base, int row, int kk, int g){
  const int m = row & 31;
  const char* rp = base + row*256;
  s16x4 lo = *(const s16x4*)(rp + (((kk*8 + g)     ^ m) << 3));
  s16x4 hi = *(const s16x4*)(rp + (((kk*8 + 4 + g) ^ m) << 3));
  s16x8 r = {lo[0],lo[1],lo[2],lo[3],hi[0],hi[1],hi[2],hi[3]};
  return r;
}

// ---------------- K1: MFMA projections ----------------
// grid 512 = 8b x 64 ntiles(64 n). block 256 = 4 waves x 16 n.
// f/g: D[co][n] -> contiguous fT/gT stores. h: D[n][co] -> hP fragment-layout 8B stores.
__global__ __launch_bounds__(256) void k_proj(
    const float* __restrict__ x,  const float* __restrict__ Wf, const float* __restrict__ bf,
    const float* __restrict__ Wg, const float* __restrict__ bg,
    const float* __restrict__ Wh, const float* __restrict__ bh,
    short* __restrict__ fT, short* __restrict__ gT, short* __restrict__ hP)
{
  __shared__ __align__(16) char sx[16384];   // x  [64 n][128 c] bf16, swizzled
  __shared__ __align__(16) char sw[40960];   // W  [160 row][128 c] bf16, swizzled (0-15 f *L2E, 16-31 g, 32-159 h)

  const int blk = blockIdx.x;
  const int b = blk & 7, ntile = blk >> 3;
  const int n0 = ntile * 64;
  const int tid = threadIdx.x;

  // stage x (transpose c-major -> [n][c]), bf16 RNE
  {
    const int cbase = tid >> 4;           // 0..15
    const int nj = (tid & 15) * 4;        // 0..60
    #pragma unroll
    for (int p = 0; p < 8; ++p){
      const int c = p*16 + cbase;
      f32x4 v = *(const f32x4*)(x + ((size_t)(b*128 + c))*NN + n0 + nj);
      #pragma unroll
      for (int e = 0; e < 4; ++e){
        const int n = nj + e;
        const int off = n*256 + ((((c>>2) ^ (n & 31))) << 3) + ((c & 3) << 1);
        *(short*)(sx + off) = f2bf(v[e]);
      }
    }
  }
  // stage W, bf16 trunc (Wf scaled by log2e)
  {
    #pragma unroll
    for (int p = 0; p < 20; ++p){
      const int id = p*256 + tid;          // 0..5119
      const int row = id >> 5;             // 0..159
      const int q = id & 31;               // float4 idx, c = q*4
      const float* src; float scale = 1.0f;
      if (row < 16)      { src = Wf + row*128;      scale = LOG2E; }
      else if (row < 32) { src = Wg + (row-16)*128; }
      else               { src = Wh + (row-32)*128; }
      f32x4 v = *(const f32x4*)(src + q*4);
      unsigned u0 = pack2(v[0]*scale, v[1]*scale);
      unsigned u1 = pack2(v[2]*scale, v[3]*scale);
      const int off = row*256 + ((q ^ (row & 31)) << 3);
      *(unsigned long long*)(sw + off) = ((unsigned long long)u1 << 32) | u0;
    }
  }
  __syncthreads();

  const int w = tid >> 6, l = tid & 63;
  const int g = l >> 4, lm = l & 15;
  const int nn = w*16 + lm;                // local n row for x frags
  const int nglob = n0 + w*16 + lm;

  s16x8 xf[4];
  #pragma unroll
  for (int kk = 0; kk < 4; ++kk) xf[kk] = frag_read(sx, nn, kk, g);

  // ---- f ----
  {
    f32x4 acc;
    f32x4 bv = *(const f32x4*)(bf + 4*g);
    #pragma unroll
    for (int i=0;i<4;++i) acc[i] = bv[i] * LOG2E;
    #pragma unroll
    for (int kk = 0; kk < 4; ++kk)
      acc = __builtin_amdgcn_mfma_f32_16x16x32_bf16(frag_read(sw, lm, kk, g), xf[kk], acc, 0,0,0);
    unsigned u0 = pack2(acc[0], acc[1]);
    unsigned u1 = pack2(acc[2], acc[3]);
    *(unsigned long long*)(fT + ((size_t)b*NN + nglob)*16 + 4*g) = ((unsigned long long)u1 << 32) | u0;
  }
  // ---- g ----
  {
    f32x4 acc = *(const f32x4*)(bg + 4*g);
    #pragma unroll
    for (int kk = 0; kk < 4; ++kk)
      acc = __builtin_amdgcn_mfma_f32_16x16x32_bf16(frag_read(sw, 16+lm, kk, g), xf[kk], acc, 0,0,0);
    unsigned u0 = pack2(acc[0], acc[1]);
    unsigned u1 = pack2(acc[2], acc[3]);
    *(unsigned long long*)(gT + ((size_t)b*NN + nglob)*16 + 4*g) = ((unsigned long long)u1 << 32) | u0;
  }
  // ---- h ----
  {
    const int nc  = ntile*2 + (w >> 1);
    const int tau = w & 1;
    #pragma unroll
    for (int ct = 0; ct < 8; ++ct){
      const float bb = bh[ct*16 + lm];
      f32x4 acc = {bb, bb, bb, bb};
      #pragma unroll
      for (int kk = 0; kk < 4; ++kk)
        acc = __builtin_amdgcn_mfma_f32_16x16x32_bf16(xf[kk], frag_read(sw, 32 + ct*16 + lm, kk, g), acc, 0,0,0);
      unsigned u0 = pack2(acc[0], acc[1]);
      unsigned u1 = pack2(acc[2], acc[3]);
      const int row = ct*64 + g*16 + lm;
      *(unsigned long long*)((char*)hP + (((size_t)(b*128 + nc))*512 + row)*16 + tau*8)
          = ((unsigned long long)u1 << 32) | u0;
    }
  }
}

// ---------------- K2: L[n] = -log2( sum_m exp2(S'[n][m]) ) ----------------
__global__ __launch_bounds__(512,4) void k_stats(
    const short* __restrict__ fT, const short* __restrict__ gT, float* __restrict__ Lrow)
{
  __shared__ float sm[2][4][16];
  const int blk = blockIdx.x;
  const int b = blk & 7, ntile = blk >> 3;
  const int tid = threadIdx.x;
  const int w = tid >> 6, l = tid & 63;
  const int g = l >> 4, lm = l & 15;
  const int ns = w & 3, mh = w >> 2;
  const int n0 = ntile*64 + ns*16;
  const f32x4 zero4 = {0.f,0.f,0.f,0.f};

  s16x4 f4 = *(const s16x4*)(fT + ((size_t)b*NN + n0 + lm)*16 + 4*g);
  s16x8 fa = {f4[0],f4[1],f4[2],f4[3],0,0,0,0};

  const short* gTb = gT + ((size_t)b*NN + mh*2048 + lm)*16 + 4*g;

  f32x4 rs = {0.f,0.f,0.f,0.f};
  #pragma unroll 1
  for (int it=0; it<32; ++it){
    #pragma unroll
    for (int j=0;j<4;++j){
      s16x4 g4 = *(const s16x4*)(gTb + it*1024 + j*256);
      s16x8 gb = {g4[0],g4[1],g4[2],g4[3],0,0,0,0};
      f32x4 d = __builtin_amdgcn_mfma_f32_16x16x32_bf16(fa, gb, zero4, 0,0,0);
      #pragma unroll
      for (int i=0;i<4;++i) rs[i] += __builtin_amdgcn_exp2f(d[i]);
    }
  }
  #pragma unroll
  for (int i=0;i<4;++i){
    #pragma unroll
    for (int mask=1; mask<16; mask<<=1) rs[i] += __shfl_xor(rs[i], mask);
  }
  if (lm == 0){
    #pragma unroll
    for (int i=0;i<4;++i) sm[mh][ns][4*g+i] = rs[i];
  }
  __syncthreads();
  if (mh == 0 && lm == 0){
    #pragma unroll
    for (int i=0;i<4;++i){
      float z = rs[i] + sm[1][ns][4*g+i];
      Lrow[(size_t)b*NN + n0 + 4*g + i] = -__log2f(z);
    }
  }
}

// ---------------- K3: out = x + gamma * sum_n h[c][n] * exp2(S'[n][m] + L[n]) ----------------
__global__ __launch_bounds__(512,4) void k_attend(
    const float* __restrict__ x, const short* __restrict__ fT, const short* __restrict__ gT,
    const short* __restrict__ hP, const float* __restrict__ Lrow,
    const float* __restrict__ gamma, float* __restrict__ out)
{
  __shared__ __align__(16) char lds[65536];

  const int blk = blockIdx.x;
  const int b = blk & 7, mtile = blk >> 3;
  const int tid = threadIdx.x;
  const int w = tid >> 6, l = tid & 63;
  const int g = l >> 4, lm = l & 15;
  const int mw = w & 1, nq = w >> 1;
  const int m0w = mtile*64 + mw*32;
  const int nbase = nq*1024;
  const f32x4 zero4 = {0.f,0.f,0.f,0.f};

  char* ring = lds + nq*16384;

  const short* hPs = hP + ((size_t)b*128 + nq*32)*4096;
  const short* fTb = fT + ((size_t)b*NN + nbase + lm)*16 + 4*g;
  const float* Lb  = Lrow + (size_t)b*NN + nbase + 4*g;

  s16x4 g40 = *(const s16x4*)(gT + ((size_t)b*NN + m0w      + lm)*16 + 4*g);
  s16x4 g41 = *(const s16x4*)(gT + ((size_t)b*NN + m0w + 16 + lm)*16 + 4*g);
  s16x8 gb0 = {g40[0],g40[1],g40[2],g40[3],0,0,0,0};
  s16x8 gb1 = {g41[0],g41[1],g41[2],g41[3],0,0,0,0};

  f32x4 acc0[8], acc1[8];
  #pragma unroll
  for (int cs=0;cs<8;++cs){ acc0[cs] = zero4; acc1[cs] = zero4; }

  s16x8 sreg[4];
  {
    const short* src = hPs + mw*2048 + l*8;
    #pragma unroll
    for (int j=0;j<4;++j) sreg[j] = *(const s16x8*)(src + j*512);
    char* wb = ring + (mw*256 + l)*16;
    #pragma unroll
    for (int j=0;j<4;++j) *(s16x8*)(wb + j*1024) = sreg[j];
  }
  __syncthreads();

  #pragma unroll 1
  for (int it=0; it<32; ++it){
    const int buf = it & 1;
    if (it < 31){
      const short* src = hPs + (it+1)*4096 + mw*2048 + l*8;
      #pragma unroll
      for (int j=0;j<4;++j) sreg[j] = *(const s16x8*)(src + j*512);
    }

    s16x4 fa4a = *(const s16x4*)(fTb + it*512);
    s16x4 fa4b = *(const s16x4*)(fTb + it*512 + 256);
    f32x4 C0 = *(const f32x4*)(Lb + it*32);
    f32x4 C1 = *(const f32x4*)(Lb + it*32 + 16);
    s16x8 fa0 = {fa4a[0],fa4a[1],fa4a[2],fa4a[3],0,0,0,0};
    s16x8 fa1 = {fa4b[0],fa4b[1],fa4b[2],fa4b[3],0,0,0,0};

    f32x4 d00 = __builtin_amdgcn_mfma_f32_16x16x32_bf16(fa0, gb0, C0, 0,0,0);
    f32x4 d10 = __builtin_amdgcn_mfma_f32_16x16x32_bf16(fa1, gb0, C1, 0,0,0);
    f32x4 d01 = __builtin_amdgcn_mfma_f32_16x16x32_bf16(fa0, gb1, C0, 0,0,0);
    f32x4 d11 = __builtin_amdgcn_mfma_f32_16x16x32_bf16(fa1, gb1, C1, 0,0,0);

    union { unsigned u[4]; s16x8 v; } A0, A1;
    A0.u[0] = pack2(__builtin_amdgcn_exp2f(d00[0]), __builtin_amdgcn_exp2f(d00[1]));
    A0.u[1] = pack2(__builtin_amdgcn_exp2f(d00[2]), __builtin_amdgcn_exp2f(d00[3]));
    A0.u[2] = pack2(__builtin_amdgcn_exp2f(d10[0]), __builtin_amdgcn_exp2f(d10[1]));
    A0.u[3] = pack2(__builtin_amdgcn_exp2f(d10[2]), __builtin_amdgcn_exp2f(d10[3]));
    A1.u[0] = pack2(__builtin_amdgcn_exp2f(d01[0]), __builtin_amdgcn_exp2f(d01[1]));
    A1.u[1] = pack2(__builtin_amdgcn_exp2f(d01[2]), __builtin_amdgcn_exp2f(d01[3]));
    A1.u[2] = pack2(__builtin_amdgcn_exp2f(d11[0]), __builtin_amdgcn_exp2f(d11[1]));
    A1.u[3] = pack2(__builtin_amdgcn_exp2f(d11[2]), __builtin_amdgcn_exp2f(d11[3]));

    const char* rb = ring + buf*8192 + l*16;
    #pragma unroll
    for (int cs=0; cs<8; ++cs){
      s16x8 hb = *(const s16x8*)(rb + cs*1024);
      acc0[cs] = __builtin_amdgcn_mfma_f32_16x16x32_bf16(A0.v, hb, acc0[cs], 0,0,0);
      acc1[cs] = __builtin_amdgcn_mfma_f32_16x16x32_bf16(A1.v, hb, acc1[cs], 0,0,0);
    }
    __syncthreads();
    if (it < 31){
      char* wb = ring + (buf^1)*8192 + (mw*256 + l)*16;
      #pragma unroll
      for (int j=0;j<4;++j) *(s16x8*)(wb + j*1024) = sreg[j];
    }
    __syncthreads();
  }

  float* redA = (float*)lds;
  float* redB = (float*)(lds + 32768);
  if (nq == 1 || nq == 3){
    float* rp = (nq==1)? redA : redB;
    #pragma unroll
    for (int h=0; h<2; ++h)
      #pragma unroll
      for (int cs=0; cs<8; ++cs)
        *(f32x4*)(rp + (((h*8+cs)*2 + mw)*64 + l)*4) = h ? acc1[cs] : acc0[cs];
  }
  __syncthreads();
  if (nq == 0 || nq == 2){
    const float* rp = (nq==0)? redA : redB;
    #pragma unroll
    for (int h=0; h<2; ++h)
      #pragma unroll
      for (int cs=0; cs<8; ++cs){
        f32x4 r = *(const f32x4*)(rp + (((h*8+cs)*2 + mw)*64 + l)*4);
        if (h) acc1[cs] += r; else acc0[cs] += r;
      }
  }
  __syncthreads();
  if (nq == 2){
    #pragma unroll
    for (int h=0; h<2; ++h)
      #pragma unroll
      for (int cs=0; cs<8; ++cs)
        *(f32x4*)(redA + (((h*8+cs)*2 + mw)*64 + l)*4) = h ? acc1[cs] : acc0[cs];
  }
  __syncthreads();
  if (nq == 0){
    const float gm = gamma[0];
    #pragma unroll
    for (int h=0; h<2; ++h)
      #pragma unroll
      for (int cs=0; cs<8; ++cs){
        f32x4 r = *(const f32x4*)(redA + (((h*8+cs)*2 + mw)*64 + l)*4);
        f32x4 a = (h ? acc1[cs] : acc0[cs]) + r;
        const int c = cs*16 + lm;
        const size_t base = ((size_t)(b*128 + c))*NN + m0w + h*16 + 4*g;
        f32x4 xv = *(const f32x4*)(x + base);
        f32x4 ov;
        #pragma unroll
        for (int i=0;i<4;++i) ov[i] = xv[i] + gm*a[i];
        *(f32x4*)(out + base) = ov;
      }
  }
}

extern "C" void kernel_launch(void* const* d_in, const int* in_sizes, int n_in,
                              void* d_out, int out_size, void* d_ws, size_t ws_size,
                              hipStream_t stream)
{
  const float* x     = (const float*)d_in[0];
  const float* Wf    = (const float*)d_in[1];
  const float* bf    = (const float*)d_in[2];
  const float* Wg    = (const float*)d_in[3];
  const float* bg    = (const float*)d_in[4];
  const float* Wh    = (const float*)d_in[5];
  const float* bh    = (const float*)d_in[6];
  const float* gamma = (const float*)d_in[7];
  float* out = (float*)d_out;

  short* fT   = (short*)d_ws;                    // [B][N][16] bf16 (*log2e)
  short* gT   = fT + (size_t)BB*NN*16;           // [B][N][16] bf16
  short* hP   = gT + (size_t)BB*NN*16;           // [B][128nc][512row][8e] bf16 fragment layout
  float* Lrow = (float*)(hP + (size_t)BB*CC*NN); // [B][N]

  k_proj  <<<BB*64, 256, 0, stream>>>(x, Wf, bf, Wg, bg, Wh, bh, fT, gT, hP);
  k_stats <<<BB*64, 512, 0, stream>>>(fT, gT, Lrow);
  k_attend<<<BB*64, 512, 0, stream>>>(x, fT, gT, hP, Lrow, gamma, out);
}